// Round 11
// baseline (151.039 us; speedup 1.0000x reference)
//
#include <hip/hip_runtime.h>
#include <hip/hip_bf16.h>

// Self-attention, N=8192, C=256, fp32 in/out, bf16 MFMA internally.
// proj (Q,K bf16; V transposed; Q pre-scaled by log2e/16)
//   -> flash attention: 256-thr blocks (4 waves x 32 Q-rows, Qtile 128),
//      KVB=64, TWO independent blocks per CU (phase-desynced so one block's
//      MFMA overlaps the other's softmax), single-buffered LDS (64 KB/block),
//      global_load_lds staging, swapped QK^T (lane-local softmax), permlane
//      P-shuffle, split-per-XCD L2 pinning, defer-rescale.
//   -> combine (merge 8 splits, divide by l).
//
// ws: [0,4Mi) qb bf16[8192][256]
//     [4Mi,8Mi) kb bf16[8192][256]
//     [8Mi,12Mi) vt bf16[256][8192]
//     [12Mi,44Mi) Opart bf16[8][8192][256]
//     [44Mi,+256Ki) Mpart f32[8][8192]
//     [+256Ki,+512Ki) Lpart f32[8][8192]     total 44.5 MiB

typedef short short8 __attribute__((ext_vector_type(8)));
typedef float f32x4 __attribute__((ext_vector_type(4)));
typedef float f32x16 __attribute__((ext_vector_type(16)));
typedef unsigned int u32x4 __attribute__((ext_vector_type(4)));

#define AS1 __attribute__((address_space(1)))
#define AS3 __attribute__((address_space(3)))

static __device__ __forceinline__ void gl_lds16(const void* g, void* l) {
    __builtin_amdgcn_global_load_lds((const AS1 unsigned int*)g,
                                     (AS3 unsigned int*)l, 16, 0, 0);
}

static __device__ __forceinline__ unsigned short f2bf(float f) {
    __hip_bfloat16 h = __float2bfloat16(f);
    return __builtin_bit_cast(unsigned short, h);
}
static __device__ __forceinline__ float bf2f(unsigned short u) {
    unsigned x = ((unsigned)u) << 16;
    return __builtin_bit_cast(float, x);
}
static __device__ __forceinline__ float exp2_fast(float x) {
    float r; asm("v_exp_f32 %0, %1" : "=v"(r) : "v"(x)); return r;
}
static __device__ __forceinline__ unsigned cvt_pk_bf16(float lo, float hi) {
    unsigned r;
    asm("v_cvt_pk_bf16_f32 %0, %1, %2" : "=v"(r) : "v"(lo), "v"(hi));
    return r;
}

static __device__ __forceinline__ short8 pack8(float4 a, float4 b) {
    short8 v;
    v[0] = (short)f2bf(a.x); v[1] = (short)f2bf(a.y);
    v[2] = (short)f2bf(a.z); v[3] = (short)f2bf(a.w);
    v[4] = (short)f2bf(b.x); v[5] = (short)f2bf(b.y);
    v[6] = (short)f2bf(b.z); v[7] = (short)f2bf(b.w);
    return v;
}

// ---------------- projection (unchanged; validated rounds 1-10) ------------
__global__ __launch_bounds__(256) void proj_kernel(
    const float* __restrict__ x, const float* __restrict__ Wq,
    const float* __restrict__ Wk, const float* __restrict__ Wv,
    unsigned short* __restrict__ qb, unsigned short* __restrict__ kb,
    unsigned short* __restrict__ vt)
{
    const int mb = blockIdx.x, nb = blockIdx.y;
    __shared__ unsigned short xs[64 * 256];
    __shared__ unsigned short wsh[64 * 256];
    const int tid = threadIdx.x;
    const int wid = tid >> 6, lane = tid & 63;
    const int l15 = lane & 15, kg = lane >> 4;

    for (int i = 0; i < 8; ++i) {
        int id = i * 256 + tid;
        int r = id >> 5, c = id & 31;
        {
            const float* g = x + (size_t)(mb * 64 + r) * 256 + c * 8;
            float4 f0 = *(const float4*)g, f1 = *(const float4*)(g + 4);
            *(short8*)&xs[r * 256 + ((c ^ (r & 7)) * 8)] = pack8(f0, f1);
        }
        {
            const float* g = Wq + (size_t)(nb * 64 + r) * 256 + c * 8;
            float4 f0 = *(const float4*)g, f1 = *(const float4*)(g + 4);
            *(short8*)&wsh[r * 256 + ((c ^ (r & 7)) * 8)] = pack8(f0, f1);
        }
    }
    __syncthreads();

    const int arow = wid * 16 + l15;
    short8 a[8];
#pragma unroll
    for (int ks = 0; ks < 8; ++ks)
        a[ks] = *(const short8*)&xs[arow * 256 + (((ks * 4 + kg) ^ (arow & 7)) * 8)];

    for (int w = 0; w < 3; ++w) {
        const float scale = (w == 0) ? 0.09016844005555f : 1.0f; // log2(e)/16
#pragma unroll
        for (int nt = 0; nt < 4; ++nt) {
            f32x4 acc = {0.f, 0.f, 0.f, 0.f};
            const int brow = nt * 16 + l15;
#pragma unroll
            for (int ks = 0; ks < 8; ++ks) {
                short8 b = *(const short8*)&wsh[brow * 256 + (((ks * 4 + kg) ^ (brow & 7)) * 8)];
                acc = __builtin_amdgcn_mfma_f32_16x16x32_bf16(a[ks], b, acc, 0, 0, 0);
            }
            const int gcol = nb * 64 + nt * 16 + l15;
#pragma unroll
            for (int r = 0; r < 4; ++r) {
                const int grow = mb * 64 + wid * 16 + kg * 4 + r;
                unsigned short h = f2bf(acc[r] * scale);
                if (w == 0)      qb[(size_t)grow * 256 + gcol] = h;
                else if (w == 1) kb[(size_t)grow * 256 + gcol] = h;
                else             vt[(size_t)gcol * 8192 + grow] = h;
            }
        }
        if (w < 2) {
            __syncthreads();
            const float* Wn = (w == 0) ? Wk : Wv;
            for (int i = 0; i < 8; ++i) {
                int id = i * 256 + tid;
                int r = id >> 5, c = id & 31;
                const float* g = Wn + (size_t)(nb * 64 + r) * 256 + c * 8;
                float4 f0 = *(const float4*)g, f1 = *(const float4*)(g + 4);
                *(short8*)&wsh[r * 256 + ((c ^ (r & 7)) * 8)] = pack8(f0, f1);
            }
            __syncthreads();
        }
    }
}

// ---------------- flash attention: 4 waves x 32 Q-rows, KVB=64 -------------
// grid 512 flat: split = bid&7 (XCD-pinned KV slice), qblk = bid>>3.
// Qtile 128/block, 2 blocks/CU (independent barriers -> phase desync).
// Single-buffered LDS 64 KB/block; DMA staged each iter; split = 16 iters.
__global__ __launch_bounds__(256, 2) void attn_kernel(
    const unsigned short* __restrict__ qb, const unsigned short* __restrict__ kb,
    const unsigned short* __restrict__ vt,
    unsigned short* __restrict__ Opart, float* __restrict__ Mpart,
    float* __restrict__ Lpart)
{
    __shared__ unsigned short Ks[64 * 256];      // 32 KB
    __shared__ unsigned short Vs[256 * 64];      // 32 KB
    const int bid = blockIdx.x;
    const int split = bid & 7, qblk = bid >> 3;
    const int tid = threadIdx.x, wid = tid >> 6, lane = tid & 63;
    const int l31 = lane & 31, hi = lane >> 5;
    const int qrow0 = qblk * 128 + wid * 32;
    const int kv0 = split * 1024;

    // Q fragments: B-operand layout (col=q=l31, k=hi*8+j per 16-d step). 64 VGPR
    short8 qf[16];
#pragma unroll
    for (int s = 0; s < 16; ++s)
        qf[s] = *(const short8*)(qb + (size_t)(qrow0 + l31) * 256 + s * 16 + hi * 8);

    f32x16 accO[8];
#pragma unroll
    for (int i = 0; i < 8; ++i) accO[i] = (f32x16)(0.f);
    float mrow = -1e30f, lrow = 0.f;

    // staging lane decomposition (global addr pre-swizzled; LDS dest linear)
    const int kro = lane >> 5, kc = lane & 31;   // K: 2 rows x 32 chunks / instr
    const int vro = lane >> 3, vc = lane & 7;    // V: 8 rows x 8 chunks / instr

    // hoisted V-read bases (content chunk uniform across lanes; dt -> imm)
    int vboff[4];
#pragma unroll
    for (int s2 = 0; s2 < 4; ++s2) {
        const int cc = s2 * 2 + hi;
        vboff[s2] = l31 * 64 + ((cc ^ (l31 & 7)) * 8);
    }

    for (int t = 0; t < 16; ++t) {
        // ---- stage tile t (single buffer: all reads of t-1 done at bottom
        //      barrier of previous iteration) ----
        {
            const unsigned short* kbase = kb + (size_t)(kv0 + t * 64) * 256;
#pragma unroll
            for (int i = 0; i < 8; ++i) {
                const int r0 = (i * 4 + wid) * 2;
                const int row = r0 + kro;
                const int c = kc ^ (row & 7);
                gl_lds16(kbase + row * 256 + c * 8, &Ks[r0 * 256]);
            }
            const unsigned short* vbase = vt + kv0 + t * 64;
#pragma unroll
            for (int i = 0; i < 8; ++i) {
                const int r0 = (i * 4 + wid) * 8;
                const int row = r0 + vro;
                const int c = vc ^ (row & 7);
                gl_lds16(vbase + (size_t)row * 8192 + c * 8, &Vs[r0 * 64]);
            }
        }
        asm volatile("s_waitcnt vmcnt(0)" ::: "memory");
        __builtin_amdgcn_sched_barrier(0);
        __builtin_amdgcn_s_barrier();            // tile t fully in LDS

        // ---- S^T = K @ Q^T : D col = q (lane-local row softmax) ----
        f32x16 s0 = (f32x16)(0.f), s1 = (f32x16)(0.f);
        __builtin_amdgcn_s_setprio(1);
#pragma unroll
        for (int s = 0; s < 16; ++s) {
            const int cc = s * 2 + hi;
            short8 kf0 = *(const short8*)&Ks[(l31) * 256 + ((cc ^ (l31 & 7)) * 8)];
            short8 kf1 = *(const short8*)&Ks[(32 + l31) * 256 + ((cc ^ (l31 & 7)) * 8)];
            s0 = __builtin_amdgcn_mfma_f32_32x32x16_bf16(kf0, qf[s], s0, 0, 0, 0);
            s1 = __builtin_amdgcn_mfma_f32_32x32x16_bf16(kf1, qf[s], s1, 0, 0, 0);
        }
        __builtin_amdgcn_s_setprio(0);

        // ---- online softmax: lane owns row q=l31 (halves split across hi) --
        float mt[16];
#pragma unroll
        for (int i = 0; i < 16; ++i) mt[i] = fmaxf(s0[i], s1[i]);
#pragma unroll
        for (int off = 8; off >= 1; off >>= 1)
#pragma unroll
            for (int i = 0; i < 8; ++i)
                if (i < off) mt[i] = fmaxf(mt[i], mt[i + off]);
        float mx = fmaxf(mt[0], __shfl_xor(mt[0], 32));

        if (!__all(mx <= mrow + 10.0f)) {   // deferred rescale (T13)
            const float mnew = fmaxf(mrow, mx);
            const float alpha = exp2_fast(mrow - mnew);
            float aR[16];
#pragma unroll
            for (int reg = 0; reg < 16; ++reg) {
                const int R = (reg & 3) + 8 * (reg >> 2) + 4 * hi;
                aR[reg] = __shfl(alpha, R);
            }
#pragma unroll
            for (int dt = 0; dt < 8; ++dt)
#pragma unroll
                for (int reg = 0; reg < 16; ++reg) accO[dt][reg] *= aR[reg];
            lrow *= alpha;
            mrow = mnew;
        }
#pragma unroll
        for (int i = 0; i < 16; ++i) {
            s0[i] = exp2_fast(s0[i] - mrow);
            s1[i] = exp2_fast(s1[i] - mrow);
        }
        float st[16];
#pragma unroll
        for (int i = 0; i < 16; ++i) st[i] = s0[i] + s1[i];
#pragma unroll
        for (int off = 8; off >= 1; off >>= 1)
#pragma unroll
            for (int i = 0; i < 8; ++i)
                if (i < off) st[i] = st[i] + st[i + off];
        lrow += st[0] + __shfl_xor(st[0], 32);

        // ---- P -> A-fragments: cvt_pk pairs + permlane32_swap (no LDS) ----
        short8 pa[4];
#pragma unroll
        for (int s = 0; s < 4; ++s) {
            const f32x16& P = (s >> 1) ? s1 : s0;
            const int q0 = 8 * (s & 1);
            unsigned X0 = cvt_pk_bf16(P[q0 + 0], P[q0 + 1]);
            unsigned X1 = cvt_pk_bf16(P[q0 + 2], P[q0 + 3]);
            unsigned Y0 = cvt_pk_bf16(P[q0 + 4], P[q0 + 5]);
            unsigned Y1 = cvt_pk_bf16(P[q0 + 6], P[q0 + 7]);
            asm volatile("v_permlane32_swap_b32 %0, %1" : "+v"(X0), "+v"(Y0));
            asm volatile("v_permlane32_swap_b32 %0, %1" : "+v"(X1), "+v"(Y1));
            u32x4 w = {X0, X1, Y0, Y1};
            pa[s] = __builtin_bit_cast(short8, w);
        }

        // ---- O += P @ V  (A=P from regs, B=V from LDS, imm dt offsets) ----
        __builtin_amdgcn_s_setprio(1);
#pragma unroll
        for (int dt = 0; dt < 8; ++dt) {
            f32x16 acc = accO[dt];
#pragma unroll
            for (int s = 0; s < 4; ++s) {
                short8 vf = *(const short8*)&Vs[vboff[s] + dt * 2048];
                acc = __builtin_amdgcn_mfma_f32_32x32x16_bf16(pa[s], vf, acc, 0, 0, 0);
            }
            accO[dt] = acc;
        }
        __builtin_amdgcn_s_setprio(0);

        __builtin_amdgcn_s_barrier();            // all reads of tile t done
    }

    // ---- partials out (un-normalized, bf16) ----
#pragma unroll
    for (int dt = 0; dt < 8; ++dt) {
        const int d = dt * 32 + l31;
#pragma unroll
        for (int reg = 0; reg < 16; ++reg) {
            const int R = (reg & 3) + 8 * (reg >> 2) + 4 * hi;
            const int grow = qrow0 + R;
            Opart[((size_t)split * 8192 + grow) * 256 + d] = f2bf(accO[dt][reg]);
        }
    }
    if (hi == 0) {
        const int grow = qrow0 + l31;
        Mpart[split * 8192 + grow] = mrow;
        Lpart[split * 8192 + grow] = lrow;
    }
}

// ---------------- combine the 8 KV-split partials --------------------------
__global__ __launch_bounds__(256) void combine_kernel(
    const unsigned short* __restrict__ Opart, const float* __restrict__ Mpart,
    const float* __restrict__ Lpart, float* __restrict__ out)
{
    const int idx = blockIdx.x * 256 + threadIdx.x;  // one float4 each
    const int row = idx >> 6;
    const int d = (idx & 63) * 4;
    float m[8], l[8];
#pragma unroll
    for (int s = 0; s < 8; ++s) {
        m[s] = Mpart[s * 8192 + row];
        l[s] = Lpart[s * 8192 + row];
    }
    float mm = m[0];
#pragma unroll
    for (int s = 1; s < 8; ++s) mm = fmaxf(mm, m[s]);
    float w[8], denom = 0.f;
#pragma unroll
    for (int s = 0; s < 8; ++s) { w[s] = exp2_fast(m[s] - mm); denom += l[s] * w[s]; }
    const float inv = 1.0f / denom;
    float4 acc = {0.f, 0.f, 0.f, 0.f};
#pragma unroll
    for (int s = 0; s < 8; ++s) {
        const unsigned short* p = Opart + ((size_t)s * 8192 + row) * 256 + d;
        unsigned long long u = *(const unsigned long long*)p;
        acc.x += bf2f((unsigned short)(u       & 0xffff)) * w[s];
        acc.y += bf2f((unsigned short)((u>>16) & 0xffff)) * w[s];
        acc.z += bf2f((unsigned short)((u>>32) & 0xffff)) * w[s];
        acc.w += bf2f((unsigned short)((u>>48) & 0xffff)) * w[s];
    }
    float4 r;
    r.x = acc.x * inv; r.y = acc.y * inv; r.z = acc.z * inv; r.w = acc.w * inv;
    *(float4*)(out + (size_t)row * 256 + d) = r;
}

extern "C" void kernel_launch(void* const* d_in, const int* in_sizes, int n_in,
                              void* d_out, int out_size, void* d_ws, size_t ws_size,
                              hipStream_t stream)
{
    const float* x  = (const float*)d_in[0];
    const float* Wq = (const float*)d_in[1];
    const float* Wk = (const float*)d_in[2];
    const float* Wv = (const float*)d_in[3];
    char* ws = (char*)d_ws;
    unsigned short* qb = (unsigned short*)(ws);
    unsigned short* kb = (unsigned short*)(ws + (4u << 20));
    unsigned short* vt = (unsigned short*)(ws + (8u << 20));
    unsigned short* Opart = (unsigned short*)(ws + (12u << 20));
    float* Mpart = (float*)(ws + (44u << 20));
    float* Lpart = (float*)(ws + (44u << 20) + (1u << 18));
    float* out = (float*)d_out;

    dim3 gA(128, 4);
    proj_kernel<<<gA, 256, 0, stream>>>(x, Wq, Wk, Wv, qb, kb, vt);
    attn_kernel<<<512, 256, 0, stream>>>(qb, kb, vt, Opart, Mpart, Lpart);
    combine_kernel<<<2048, 256, 0, stream>>>(Opart, Mpart, Lpart, out);
}

// Round 12
// 105.409 us; speedup vs baseline: 1.4329x; 1.4329x over previous
//
#include <hip/hip_runtime.h>
#include <hip/hip_bf16.h>

// Self-attention, N=8192, C=256, fp32 in/out, bf16 MFMA internally.
// proj (Q bf16 row-major pre-scaled log2e/16; K bf16 chunk-major
//       kbt[kv/64][d/8][kv%64][8]; V bf16 chunk-major vtc[kv/8][d][8])
//   -> flash attention: 512-thr blocks (8 waves x 32 Q-rows), 32x32x16 MFMA,
//      swapped QK^T (lane-local softmax), permlane P-shuffle; LDS tiles in
//      chunk-major layout -> all fragment reads are base+IMMEDIATE (zero
//      address VALU, back-to-back issue, minimal bank aliasing); dbuf
//      global_load_lds staging (coalesced 1KB per instr), single barrier/iter;
//      split-per-XCD L2 pinning; defer-rescale; deferred L.
//   -> combine (merge 8 splits, divide by l).
//
// ws: [0,4Mi) qb bf16[8192][256]
//     [4Mi,8Mi) kbt bf16[128][32][64][8]
//     [8Mi,12Mi) vtc bf16[1024][256][8]
//     [12Mi,44Mi) Opart bf16[8][8192][256]
//     [44Mi,+256Ki) Mpart f32[8][8192]
//     [+256Ki,+512Ki) Lpart f32[8][8192]     total 44.5 MiB

typedef short short8 __attribute__((ext_vector_type(8)));
typedef float f32x4 __attribute__((ext_vector_type(4)));
typedef float f32x16 __attribute__((ext_vector_type(16)));
typedef unsigned int u32x4 __attribute__((ext_vector_type(4)));

#define AS1 __attribute__((address_space(1)))
#define AS3 __attribute__((address_space(3)))

static __device__ __forceinline__ void gl_lds16(const void* g, void* l) {
    __builtin_amdgcn_global_load_lds((const AS1 unsigned int*)g,
                                     (AS3 unsigned int*)l, 16, 0, 0);
}

static __device__ __forceinline__ unsigned short f2bf(float f) {
    __hip_bfloat16 h = __float2bfloat16(f);
    return __builtin_bit_cast(unsigned short, h);
}
static __device__ __forceinline__ float bf2f(unsigned short u) {
    unsigned x = ((unsigned)u) << 16;
    return __builtin_bit_cast(float, x);
}
static __device__ __forceinline__ float exp2_fast(float x) {
    float r; asm("v_exp_f32 %0, %1" : "=v"(r) : "v"(x)); return r;
}
static __device__ __forceinline__ unsigned cvt_pk_bf16(float lo, float hi) {
    unsigned r;
    asm("v_cvt_pk_bf16_f32 %0, %1, %2" : "=v"(r) : "v"(lo), "v"(hi));
    return r;
}

static __device__ __forceinline__ short8 pack8(float4 a, float4 b) {
    short8 v;
    v[0] = (short)f2bf(a.x); v[1] = (short)f2bf(a.y);
    v[2] = (short)f2bf(a.z); v[3] = (short)f2bf(a.w);
    v[4] = (short)f2bf(b.x); v[5] = (short)f2bf(b.y);
    v[6] = (short)f2bf(b.z); v[7] = (short)f2bf(b.w);
    return v;
}

// ---------------- projection (compute identical to R1-R11; K/V layouts new) -
__global__ __launch_bounds__(256) void proj_kernel(
    const float* __restrict__ x, const float* __restrict__ Wq,
    const float* __restrict__ Wk, const float* __restrict__ Wv,
    unsigned short* __restrict__ qb, unsigned short* __restrict__ kbt,
    unsigned short* __restrict__ vtc)
{
    const int mb = blockIdx.x, nb = blockIdx.y;
    __shared__ unsigned short xs[64 * 256];
    __shared__ unsigned short wsh[64 * 256];
    const int tid = threadIdx.x;
    const int wid = tid >> 6, lane = tid & 63;
    const int l15 = lane & 15, kg = lane >> 4;

    for (int i = 0; i < 8; ++i) {
        int id = i * 256 + tid;
        int r = id >> 5, c = id & 31;
        {
            const float* g = x + (size_t)(mb * 64 + r) * 256 + c * 8;
            float4 f0 = *(const float4*)g, f1 = *(const float4*)(g + 4);
            *(short8*)&xs[r * 256 + ((c ^ (r & 7)) * 8)] = pack8(f0, f1);
        }
        {
            const float* g = Wq + (size_t)(nb * 64 + r) * 256 + c * 8;
            float4 f0 = *(const float4*)g, f1 = *(const float4*)(g + 4);
            *(short8*)&wsh[r * 256 + ((c ^ (r & 7)) * 8)] = pack8(f0, f1);
        }
    }
    __syncthreads();

    const int arow = wid * 16 + l15;
    short8 a[8];
#pragma unroll
    for (int ks = 0; ks < 8; ++ks)
        a[ks] = *(const short8*)&xs[arow * 256 + (((ks * 4 + kg) ^ (arow & 7)) * 8)];

    for (int w = 0; w < 3; ++w) {
        const float scale = (w == 0) ? 0.09016844005555f : 1.0f; // log2(e)/16
#pragma unroll
        for (int nt = 0; nt < 4; ++nt) {
            f32x4 acc = {0.f, 0.f, 0.f, 0.f};
            const int brow = nt * 16 + l15;
#pragma unroll
            for (int ks = 0; ks < 8; ++ks) {
                short8 b = *(const short8*)&wsh[brow * 256 + (((ks * 4 + kg) ^ (brow & 7)) * 8)];
                acc = __builtin_amdgcn_mfma_f32_16x16x32_bf16(a[ks], b, acc, 0, 0, 0);
            }
            const int gcol = nb * 64 + nt * 16 + l15;
#pragma unroll
            for (int r = 0; r < 4; ++r) {
                const int grow = mb * 64 + wid * 16 + kg * 4 + r;
                unsigned short h = f2bf(acc[r] * scale);
                if (w == 0) {
                    qb[(size_t)grow * 256 + gcol] = h;
                } else if (w == 1) {
                    // kbt[kv/64][d/8][kv%64][8]
                    kbt[(size_t)(grow >> 6) * 16384 + (gcol >> 3) * 512
                        + (grow & 63) * 8 + (gcol & 7)] = h;
                } else {
                    // vtc[kv/8][d][8]
                    vtc[(size_t)(grow >> 3) * 2048 + (size_t)gcol * 8 + (grow & 7)] = h;
                }
            }
        }
        if (w < 2) {
            __syncthreads();
            const float* Wn = (w == 0) ? Wk : Wv;
            for (int i = 0; i < 8; ++i) {
                int id = i * 256 + tid;
                int r = id >> 5, c = id & 31;
                const float* g = Wn + (size_t)(nb * 64 + r) * 256 + c * 8;
                float4 f0 = *(const float4*)g, f1 = *(const float4*)(g + 4);
                *(short8*)&wsh[r * 256 + ((c ^ (r & 7)) * 8)] = pack8(f0, f1);
            }
            __syncthreads();
        }
    }
}

// ---------------- flash attention: 8 waves x 32 Q-rows, KVB=64 -------------
// grid 256 flat: split = bid&7 (XCD-pinned KV slice), qblk = bid>>3.
// LDS tiles chunk-major: Ks[chunk cc][row][8], Vs[kvchunk cc][d][8].
// All fragment reads: lane base + compile-time immediate. Dbuf, 1 barrier/iter.
__global__ __launch_bounds__(512, 1) void attn_kernel(
    const unsigned short* __restrict__ qb, const unsigned short* __restrict__ kbt,
    const unsigned short* __restrict__ vtc,
    unsigned short* __restrict__ Opart, float* __restrict__ Mpart,
    float* __restrict__ Lpart)
{
    __shared__ unsigned short Ks[2][32 * 64 * 8];   // [cc][row][8]  2 x 32 KB
    __shared__ unsigned short Vs[2][8 * 256 * 8];   // [cc][d][8]    2 x 32 KB
    const int bid = blockIdx.x;
    const int split = bid & 7, qblk = bid >> 3;
    const int tid = threadIdx.x, wid = tid >> 6, lane = tid & 63;
    const int l31 = lane & 31, hi = lane >> 5;
    const int qrow0 = qblk * 256 + wid * 32;
    const int kv0 = split * 1024;

    // Q fragments: B-operand layout (col=q=l31, k=hi*8+j per 16-d step). 64 VGPR
    short8 qf[16];
#pragma unroll
    for (int s = 0; s < 16; ++s)
        qf[s] = *(const short8*)(qb + (size_t)(qrow0 + l31) * 256 + s * 16 + hi * 8);

    f32x16 accO[8];
#pragma unroll
    for (int i = 0; i < 8; ++i) accO[i] = (f32x16)(0.f);
    f32x16 lacc = (f32x16)(0.f);
    float mrow = -1e30f;

    // per-lane LDS read bases (elements)
    const int kbase_e = hi * 512 + l31 * 8;    // K: + s*1024 (+256 for row+32)
    const int vbase_e = hi * 2048 + l31 * 8;   // V: + s2*4096 + dt*256

    // staging: per wave 4 K-instrs (cc = i*8+wid) + 4 V-instrs (vi = i*8+wid)
    auto stage = [&](int t, int b) {
        const size_t g = (size_t)(split * 16 + t);
        const unsigned short* ksrc = kbt + g * 16384 + lane * 8;
#pragma unroll
        for (int i = 0; i < 4; ++i) {
            const int cc = i * 8 + wid;
            gl_lds16(ksrc + cc * 512, &Ks[b][cc * 512]);
        }
        const size_t kcb = (size_t)(split * 128 + t * 8);
        const unsigned short* vsrc = vtc + kcb * 2048 + lane * 8;
#pragma unroll
        for (int i = 0; i < 4; ++i) {
            const int vi = i * 8 + wid;
            const int cc = vi >> 2, b64 = vi & 3;
            gl_lds16(vsrc + cc * 2048 + b64 * 512, &Vs[b][cc * 2048 + b64 * 512]);
        }
    };

    // prologue: tile 0 staged and visible
    stage(0, 0);
    asm volatile("s_waitcnt vmcnt(0)" ::: "memory");
    __builtin_amdgcn_sched_barrier(0);
    __builtin_amdgcn_s_barrier();

    for (int t = 0; t < 16; ++t) {
        if (t < 15) stage(t + 1, (t + 1) & 1);   // prefetch rides through body

        const unsigned short* Kb = Ks[t & 1];
        const unsigned short* Vb = Vs[t & 1];

        // ---- S^T = K @ Q^T : D col = q (lane-local row softmax) ----
        f32x16 s0 = (f32x16)(0.f), s1 = (f32x16)(0.f);
        __builtin_amdgcn_s_setprio(1);
#pragma unroll
        for (int s = 0; s < 16; ++s) {
            short8 kf0 = *(const short8*)&Kb[kbase_e + s * 1024];
            short8 kf1 = *(const short8*)&Kb[kbase_e + s * 1024 + 256];
            s0 = __builtin_amdgcn_mfma_f32_32x32x16_bf16(kf0, qf[s], s0, 0, 0, 0);
            s1 = __builtin_amdgcn_mfma_f32_32x32x16_bf16(kf1, qf[s], s1, 0, 0, 0);
        }
        __builtin_amdgcn_s_setprio(0);

        // ---- online softmax: lane owns row q=l31 (halves split across hi) --
        float mt[16];
#pragma unroll
        for (int i = 0; i < 16; ++i) mt[i] = fmaxf(s0[i], s1[i]);
#pragma unroll
        for (int off = 8; off >= 1; off >>= 1)
#pragma unroll
            for (int i = 0; i < 8; ++i)
                if (i < off) mt[i] = fmaxf(mt[i], mt[i + off]);
        float mx = fmaxf(mt[0], __shfl_xor(mt[0], 32));

        if (!__all(mx <= mrow + 10.0f)) {   // deferred rescale (T13)
            const float mnew = fmaxf(mrow, mx);
            const float alpha = exp2_fast(mrow - mnew);
            float aR[16];
#pragma unroll
            for (int reg = 0; reg < 16; ++reg) {
                const int R = (reg & 3) + 8 * (reg >> 2) + 4 * hi;
                aR[reg] = __shfl(alpha, R);
            }
#pragma unroll
            for (int dt = 0; dt < 8; ++dt)
#pragma unroll
                for (int reg = 0; reg < 16; ++reg) accO[dt][reg] *= aR[reg];
            lacc = lacc * alpha;
            mrow = mnew;
        }
#pragma unroll
        for (int i = 0; i < 16; ++i) {
            s0[i] = exp2_fast(s0[i] - mrow);
            s1[i] = exp2_fast(s1[i] - mrow);
        }
        lacc = lacc + s0 + s1;               // deferred L (reduced at end)

        // ---- P -> A-fragments: cvt_pk pairs + permlane32_swap (no LDS) ----
        short8 pa[4];
#pragma unroll
        for (int s = 0; s < 4; ++s) {
            const f32x16& P = (s >> 1) ? s1 : s0;
            const int q0 = 8 * (s & 1);
            unsigned X0 = cvt_pk_bf16(P[q0 + 0], P[q0 + 1]);
            unsigned X1 = cvt_pk_bf16(P[q0 + 2], P[q0 + 3]);
            unsigned Y0 = cvt_pk_bf16(P[q0 + 4], P[q0 + 5]);
            unsigned Y1 = cvt_pk_bf16(P[q0 + 6], P[q0 + 7]);
            asm volatile("v_permlane32_swap_b32 %0, %1" : "+v"(X0), "+v"(Y0));
            asm volatile("v_permlane32_swap_b32 %0, %1" : "+v"(X1), "+v"(Y1));
            u32x4 w = {X0, X1, Y0, Y1};
            pa[s] = __builtin_bit_cast(short8, w);
        }

        // ---- O += P @ V  (A=P regs, B=V from LDS at immediate offsets) ----
        __builtin_amdgcn_s_setprio(1);
#pragma unroll
        for (int dt = 0; dt < 8; ++dt) {
            f32x16 acc = accO[dt];
#pragma unroll
            for (int s = 0; s < 4; ++s) {
                short8 vf = *(const short8*)&Vb[vbase_e + s * 4096 + dt * 256];
                acc = __builtin_amdgcn_mfma_f32_32x32x16_bf16(pa[s], vf, acc, 0, 0, 0);
            }
            accO[dt] = acc;
        }
        __builtin_amdgcn_s_setprio(0);

        // single rendezvous: own stage(t+1) landed + all reads of buf[t&1] done
        asm volatile("s_waitcnt vmcnt(0)" ::: "memory");
        __builtin_amdgcn_sched_barrier(0);
        __builtin_amdgcn_s_barrier();
    }

    // ---- deferred L reduction ----
    float lt[8];
#pragma unroll
    for (int i = 0; i < 8; ++i) lt[i] = lacc[i] + lacc[i + 8];
#pragma unroll
    for (int off = 4; off >= 1; off >>= 1)
#pragma unroll
        for (int i = 0; i < 4; ++i)
            if (i < off) lt[i] = lt[i] + lt[i + off];
    const float lrow = lt[0] + __shfl_xor(lt[0], 32);

    // ---- partials out (un-normalized, bf16) ----
#pragma unroll
    for (int dt = 0; dt < 8; ++dt) {
        const int d = dt * 32 + l31;
#pragma unroll
        for (int reg = 0; reg < 16; ++reg) {
            const int R = (reg & 3) + 8 * (reg >> 2) + 4 * hi;
            const int grow = qrow0 + R;
            Opart[((size_t)split * 8192 + grow) * 256 + d] = f2bf(accO[dt][reg]);
        }
    }
    if (hi == 0) {
        const int grow = qrow0 + l31;
        Mpart[split * 8192 + grow] = mrow;
        Lpart[split * 8192 + grow] = lrow;
    }
}

// ---------------- combine the 8 KV-split partials --------------------------
__global__ __launch_bounds__(256) void combine_kernel(
    const unsigned short* __restrict__ Opart, const float* __restrict__ Mpart,
    const float* __restrict__ Lpart, float* __restrict__ out)
{
    const int idx = blockIdx.x * 256 + threadIdx.x;  // one float4 each
    const int row = idx >> 6;
    const int d = (idx & 63) * 4;
    float m[8], l[8];
#pragma unroll
    for (int s = 0; s < 8; ++s) {
        m[s] = Mpart[s * 8192 + row];
        l[s] = Lpart[s * 8192 + row];
    }
    float mm = m[0];
#pragma unroll
    for (int s = 1; s < 8; ++s) mm = fmaxf(mm, m[s]);
    float w[8], denom = 0.f;
#pragma unroll
    for (int s = 0; s < 8; ++s) { w[s] = exp2_fast(m[s] - mm); denom += l[s] * w[s]; }
    const float inv = 1.0f / denom;
    float4 acc = {0.f, 0.f, 0.f, 0.f};
#pragma unroll
    for (int s = 0; s < 8; ++s) {
        const unsigned short* p = Opart + ((size_t)s * 8192 + row) * 256 + d;
        unsigned long long u = *(const unsigned long long*)p;
        acc.x += bf2f((unsigned short)(u       & 0xffff)) * w[s];
        acc.y += bf2f((unsigned short)((u>>16) & 0xffff)) * w[s];
        acc.z += bf2f((unsigned short)((u>>32) & 0xffff)) * w[s];
        acc.w += bf2f((unsigned short)((u>>48) & 0xffff)) * w[s];
    }
    float4 r;
    r.x = acc.x * inv; r.y = acc.y * inv; r.z = acc.z * inv; r.w = acc.w * inv;
    *(float4*)(out + (size_t)row * 256 + d) = r;
}

extern "C" void kernel_launch(void* const* d_in, const int* in_sizes, int n_in,
                              void* d_out, int out_size, void* d_ws, size_t ws_size,
                              hipStream_t stream)
{
    const float* x  = (const float*)d_in[0];
    const float* Wq = (const float*)d_in[1];
    const float* Wk = (const float*)d_in[2];
    const float* Wv = (const float*)d_in[3];
    char* ws = (char*)d_ws;
    unsigned short* qb  = (unsigned short*)(ws);
    unsigned short* kbt = (unsigned short*)(ws + (4u << 20));
    unsigned short* vtc = (unsigned short*)(ws + (8u << 20));
    unsigned short* Opart = (unsigned short*)(ws + (12u << 20));
    float* Mpart = (float*)(ws + (44u << 20));
    float* Lpart = (float*)(ws + (44u << 20) + (1u << 18));
    float* out = (float*)d_out;

    dim3 gA(128, 4);
    proj_kernel<<<gA, 256, 0, stream>>>(x, Wq, Wk, Wv, qb, kbt, vtc);
    attn_kernel<<<256, 512, 0, stream>>>(qb, kbt, vtc, Opart, Mpart, Lpart);
    combine_kernel<<<2048, 256, 0, stream>>>(Opart, Mpart, Lpart, out);
}